// Round 1
// baseline (236.741 us; speedup 1.0000x reference)
//
#include <hip/hip_runtime.h>
#include <hip/hip_bf16.h>

// Problem: single-head causal attention. B=4, T=2048, E=768, H=64.
// Inputs (setup_inputs dict order): x[4,2048,768] f32, Wk[768,64] f32, Wq, Wv.
// Output: [4,2048,64] f32.
// Strategy: bf16 MFMA 16x16x32 everywhere; flash-style online softmax (no S
// materialization). Scale+log2(e) folded into Wq so softmax uses exp2 (native).

typedef __attribute__((ext_vector_type(8))) short short8;
typedef __attribute__((ext_vector_type(4))) float f32x4;

__device__ __forceinline__ unsigned short f2bf(float f) {
    union { float f; unsigned u; } v; v.f = f;
    unsigned r = v.u + 0x7fffu + ((v.u >> 16) & 1u);  // RNE
    return (unsigned short)(r >> 16);
}

// ---- WT[192][768] bf16: n in [0,64)=Wq*(log2e/sqrt(768)), [64,128)=Wk, [128,192)=Wv
__global__ __launch_bounds__(256) void wt_kernel(const float* __restrict__ Wk,
                                                 const float* __restrict__ Wq,
                                                 const float* __restrict__ Wv,
                                                 unsigned short* __restrict__ WT) {
    const float CSCALE = 1.4426950408889634f / 27.712812921102035f;  // log2(e)/sqrt(768)
    int flat = blockIdx.x * 256 + threadIdx.x;   // [0, 147456)
    int n = flat / 768, k = flat % 768;
    int mat = n >> 6, col = n & 63;
    const float* W = (mat == 0) ? Wq : (mat == 1) ? Wk : Wv;
    float v = W[k * 64 + col];
    if (mat == 0) v *= CSCALE;
    WT[flat] = f2bf(v);
}

// ---- projections: q,k bf16 [8192][64]; v stored transposed vT[b][64h][2048t]
__global__ __launch_bounds__(256) void proj_kernel(const float* __restrict__ x,
                                                   const unsigned short* __restrict__ WT,
                                                   unsigned short* __restrict__ qws,
                                                   unsigned short* __restrict__ kws,
                                                   unsigned short* __restrict__ vT) {
    __shared__ unsigned short xs[64 * 72];    // [row][k] pad->72 (16B aligned rows)
    __shared__ unsigned short wsm[192 * 72];  // [n][k]
    int tid = threadIdx.x;
    int lane = tid & 63, wave = tid >> 6;
    int quad = lane >> 4, l16 = lane & 15;
    int wm = wave & 1, wn = wave >> 1;        // wave grid 2x2: rows 32, cols 96
    int row0 = blockIdx.x * 64;

    f32x4 acc[2][6];
    for (int mt = 0; mt < 2; ++mt)
        for (int nt = 0; nt < 6; ++nt) acc[mt][nt] = (f32x4)(0.f);

    for (int kc = 0; kc < 12; ++kc) {         // K chunks of 64
        __syncthreads();
        for (int i = 0; i < 2; ++i) {         // stage x: 64x64 f32 -> bf16
            int e = tid + 256 * i;
            int row = e >> 3, hb = (e & 7) * 8;
            const float* src = x + (size_t)(row0 + row) * 768 + kc * 64 + hb;
            float4 f0 = *(const float4*)(src);
            float4 f1 = *(const float4*)(src + 4);
            short8 pk;
            pk[0] = (short)f2bf(f0.x); pk[1] = (short)f2bf(f0.y);
            pk[2] = (short)f2bf(f0.z); pk[3] = (short)f2bf(f0.w);
            pk[4] = (short)f2bf(f1.x); pk[5] = (short)f2bf(f1.y);
            pk[6] = (short)f2bf(f1.z); pk[7] = (short)f2bf(f1.w);
            *(short8*)&xs[row * 72 + hb] = pk;
        }
        for (int i = 0; i < 6; ++i) {         // stage W chunk: 192x64 bf16
            int e = tid + 256 * i;
            int n = e >> 3, kb8 = (e & 7) * 8;
            *(short8*)&wsm[n * 72 + kb8] = *(const short8*)&WT[n * 768 + kc * 64 + kb8];
        }
        __syncthreads();
        for (int kh = 0; kh < 2; ++kh) {      // 2 k-steps of 32
            int kk = kh * 32 + quad * 8;
            short8 a[2], bfr[6];
            for (int mt = 0; mt < 2; ++mt)
                a[mt] = *(const short8*)&xs[(wm * 32 + mt * 16 + l16) * 72 + kk];
            for (int nt = 0; nt < 6; ++nt)
                bfr[nt] = *(const short8*)&wsm[(wn * 96 + nt * 16 + l16) * 72 + kk];
            for (int mt = 0; mt < 2; ++mt)
                for (int nt = 0; nt < 6; ++nt)
                    acc[mt][nt] = __builtin_amdgcn_mfma_f32_16x16x32_bf16(
                        a[mt], bfr[nt], acc[mt][nt], 0, 0, 0);
        }
    }
    __syncthreads();
    // epilogue: C-layout row=quad*4+j, col=l16 (within 16-tile)
    for (int mt = 0; mt < 2; ++mt) {
        for (int nt = 0; nt < 6; ++nt) {
            int n = wn * 96 + nt * 16 + l16;
            int mat = n >> 6, col = n & 63;
            for (int j = 0; j < 4; ++j) {
                int rloc = wm * 32 + mt * 16 + quad * 4 + j;
                unsigned short bv = f2bf(acc[mt][nt][j]);
                if (mat == 0)      qws[(size_t)(row0 + rloc) * 64 + col] = bv;
                else if (mat == 1) kws[(size_t)(row0 + rloc) * 64 + col] = bv;
                else               xs[col * 72 + rloc] = bv;   // stash v for transpose
            }
        }
    }
    __syncthreads();
    int bidx = row0 >> 11;        // batch
    int t0 = row0 & 2047;
    for (int i = 0; i < 2; ++i) { // write vT[b][h][t] coalesced
        int e = tid + 256 * i;    // [0,512)
        int c = e >> 3, rb = (e & 7) * 8;
        *(short8*)&vT[((size_t)(bidx * 64 + c)) * 2048 + t0 + rb] =
            *(const short8*)&xs[c * 72 + rb];
    }
}

// ---- flash attention: block = (32 q rows, batch b), 2 waves x 16 rows
__global__ __launch_bounds__(128) void attn_kernel(const unsigned short* __restrict__ qws,
                                                   const unsigned short* __restrict__ kws,
                                                   const unsigned short* __restrict__ vT,
                                                   float* __restrict__ out) {
    __shared__ unsigned short qs[32 * 72];   // [q][h]
    __shared__ unsigned short ks[64 * 72];   // [key][h]
    __shared__ unsigned short vs[64 * 72];   // [h][key]  (from vT: contiguous stage)
    __shared__ unsigned short ps[2][16 * 72];// per-wave P [q][key]
    int tid = threadIdx.x;
    int lane = tid & 63, wave = tid >> 6;
    int quad = lane >> 4, l16 = lane & 15;
    int bx = blockIdx.x, b = blockIdx.y;
    int q0 = bx * 32;
    size_t qbase = ((size_t)b * 2048 + q0) * 64;
    for (int i = 0; i < 2; ++i) {
        int e = tid + 128 * i;
        int r = e >> 3, hb = (e & 7) * 8;
        *(short8*)&qs[r * 72 + hb] = *(const short8*)&qws[qbase + r * 64 + hb];
    }
    __syncthreads();
    short8 aq[2];   // Q A-frags, resident whole loop
    for (int kh = 0; kh < 2; ++kh)
        aq[kh] = *(const short8*)&qs[(wave * 16 + l16) * 72 + kh * 32 + quad * 8];

    f32x4 o_acc[4];
    for (int nt = 0; nt < 4; ++nt) o_acc[nt] = (f32x4)(0.f);
    float m_run[4], l_run[4];
    int row_g[4];
    for (int j = 0; j < 4; ++j) {
        m_run[j] = -1e30f; l_run[j] = 0.f;
        row_g[j] = q0 + wave * 16 + quad * 4 + j;
    }

    int kb_max = (q0 + 31) >> 6;
    for (int kb = 0; kb <= kb_max; ++kb) {
        __syncthreads();
        size_t kvbase = ((size_t)b * 2048 + kb * 64) * 64;
        for (int i = 0; i < 4; ++i) {   // K block [64key][64h]
            int e = tid + 128 * i;
            int r = e >> 3, hb = (e & 7) * 8;
            *(short8*)&ks[r * 72 + hb] = *(const short8*)&kws[kvbase + r * 64 + hb];
        }
        for (int i = 0; i < 4; ++i) {   // V block [64h][64key] straight from vT
            int e = tid + 128 * i;
            int h = e >> 3, kyb = (e & 7) * 8;
            *(short8*)&vs[h * 72 + kyb] =
                *(const short8*)&vT[((size_t)b * 64 + h) * 2048 + kb * 64 + kyb];
        }
        __syncthreads();
        f32x4 s[4];
        for (int nt = 0; nt < 4; ++nt) s[nt] = (f32x4)(0.f);
        for (int kh = 0; kh < 2; ++kh)
            for (int nt = 0; nt < 4; ++nt) {
                short8 bk = *(const short8*)&ks[(nt * 16 + l16) * 72 + kh * 32 + quad * 8];
                s[nt] = __builtin_amdgcn_mfma_f32_16x16x32_bf16(aq[kh], bk, s[nt], 0, 0, 0);
            }
        // causal mask (logits already include scale*log2e via Wq fold)
        for (int nt = 0; nt < 4; ++nt) {
            int key = kb * 64 + nt * 16 + l16;
            for (int j = 0; j < 4; ++j)
                if (key > row_g[j]) s[nt][j] = -1e30f;
        }
        float mx[4], al[4], rs[4];
        for (int j = 0; j < 4; ++j)
            mx[j] = fmaxf(fmaxf(s[0][j], s[1][j]), fmaxf(s[2][j], s[3][j]));
        for (int off = 1; off < 16; off <<= 1)
            for (int j = 0; j < 4; ++j)
                mx[j] = fmaxf(mx[j], __shfl_xor(mx[j], off, 16));
        for (int j = 0; j < 4; ++j) {
            float mn = fmaxf(m_run[j], mx[j]);
            al[j] = exp2f(m_run[j] - mn);
            m_run[j] = mn;
            rs[j] = 0.f;
        }
        for (int nt = 0; nt < 4; ++nt)
            for (int j = 0; j < 4; ++j) {
                float p = exp2f(s[nt][j] - m_run[j]);
                rs[j] += p;
                ps[wave][(quad * 4 + j) * 72 + nt * 16 + l16] = f2bf(p);
            }
        for (int off = 1; off < 16; off <<= 1)
            for (int j = 0; j < 4; ++j)
                rs[j] += __shfl_xor(rs[j], off, 16);
        for (int j = 0; j < 4; ++j) l_run[j] = l_run[j] * al[j] + rs[j];
        for (int nt = 0; nt < 4; ++nt)
            for (int j = 0; j < 4; ++j) o_acc[nt][j] *= al[j];
        // PV: A = P[q][key] (from ps), B = V[key][h] (vs is [h][key], key-contig)
        for (int kh = 0; kh < 2; ++kh) {
            short8 ap = *(const short8*)&ps[wave][l16 * 72 + kh * 32 + quad * 8];
            for (int nt = 0; nt < 4; ++nt) {
                short8 bv = *(const short8*)&vs[(nt * 16 + l16) * 72 + kh * 32 + quad * 8];
                o_acc[nt] = __builtin_amdgcn_mfma_f32_16x16x32_bf16(ap, bv, o_acc[nt], 0, 0, 0);
            }
        }
    }
    for (int nt = 0; nt < 4; ++nt)
        for (int j = 0; j < 4; ++j)
            out[((size_t)b * 2048 + row_g[j]) * 64 + nt * 16 + l16] =
                o_acc[nt][j] / l_run[j];
}

extern "C" void kernel_launch(void* const* d_in, const int* in_sizes, int n_in,
                              void* d_out, int out_size, void* d_ws, size_t ws_size,
                              hipStream_t stream) {
    const float* x  = (const float*)d_in[0];
    const float* Wk = (const float*)d_in[1];
    const float* Wq = (const float*)d_in[2];
    const float* Wv = (const float*)d_in[3];
    float* out = (float*)d_out;
    // ws layout (bytes): WT 294912 | q 1MB | k 1MB | vT 1MB  (total ~3.3MB)
    unsigned short* WT  = (unsigned short*)d_ws;
    unsigned short* qws = (unsigned short*)((char*)d_ws + 294912);
    unsigned short* kws = (unsigned short*)((char*)d_ws + 294912 + 1048576);
    unsigned short* vT  = (unsigned short*)((char*)d_ws + 294912 + 2097152);
    wt_kernel<<<576, 256, 0, stream>>>(Wk, Wq, Wv, WT);
    proj_kernel<<<128, 256, 0, stream>>>(x, WT, qws, kws, vT);
    attn_kernel<<<dim3(64, 4), 128, 0, stream>>>(qws, kws, vT, out);
}

// Round 2
// 119.549 us; speedup vs baseline: 1.9803x; 1.9803x over previous
//
#include <hip/hip_runtime.h>
#include <hip/hip_bf16.h>

// Single-head causal attention. B=4, T=2048, E=768, H=64.
// x[4,2048,768] f32; Wk,Wq,Wv [768,64] f32. Out [4,2048,64] f32.
// R2: split-K flash decode. Key range of each 32-row q-tile is split into
// chunks of 8 key-blocks (512 keys); each (tile, split) block writes
// unnormalized partial (O, m, l); reduce kernel combines. Fixes the R1
// occupancy disaster (2.9% occupancy, 33-deep serial loop on 2 waves/CU).

typedef __attribute__((ext_vector_type(8))) short short8;
typedef __attribute__((ext_vector_type(4))) float f32x4;

#define SPLIT_KB 8          // key-blocks (of 64) per split
#define MAX_SP 5            // ceil(33/8)

__device__ __forceinline__ unsigned short f2bf(float f) {
    union { float f; unsigned u; } v; v.f = f;
    unsigned r = v.u + 0x7fffu + ((v.u >> 16) & 1u);  // RNE
    return (unsigned short)(r >> 16);
}

// ---- WT[192][768] bf16: n in [0,64)=Wq*(log2e/sqrt(768)), [64,128)=Wk, [128,192)=Wv
// coalesced reads: consecutive lanes -> consecutive col of W
__global__ __launch_bounds__(256) void wt_kernel(const float* __restrict__ Wk,
                                                 const float* __restrict__ Wq,
                                                 const float* __restrict__ Wv,
                                                 unsigned short* __restrict__ WT) {
    const float CSCALE = 1.4426950408889634f / 27.712812921102035f;  // log2(e)/sqrt(768)
    int flat = blockIdx.x * 256 + threadIdx.x;   // [0, 147456)
    int k = flat / 192, n = flat % 192;
    int mat = n >> 6, col = n & 63;
    const float* W = (mat == 0) ? Wq : (mat == 1) ? Wk : Wv;
    float v = W[k * 64 + col];
    if (mat == 0) v *= CSCALE;
    WT[n * 768 + k] = f2bf(v);
}

// ---- projections, grid (128, 3): block = 64 rows x 64 cols of matrix my
__global__ __launch_bounds__(256) void proj_kernel(const float* __restrict__ x,
                                                   const unsigned short* __restrict__ WT,
                                                   unsigned short* __restrict__ qws,
                                                   unsigned short* __restrict__ kws,
                                                   unsigned short* __restrict__ vT) {
    __shared__ unsigned short xs[64 * 72];    // [row][k] pad->72
    __shared__ unsigned short wsm[64 * 72];   // [n][k]
    int tid = threadIdx.x;
    int lane = tid & 63, wave = tid >> 6;
    int quad = lane >> 4, l16 = lane & 15;
    int wm = wave & 1, wn = wave >> 1;        // 2x2 waves: 32 rows x 32 cols each
    int row0 = blockIdx.x * 64;
    int my = blockIdx.y;                      // 0=q 1=k 2=v

    f32x4 acc[2][2];
    for (int mt = 0; mt < 2; ++mt)
        for (int nt = 0; nt < 2; ++nt) acc[mt][nt] = (f32x4)(0.f);

    for (int kc = 0; kc < 12; ++kc) {
        __syncthreads();
        for (int i = 0; i < 2; ++i) {         // stage x 64x64 f32 -> bf16
            int e = tid + 256 * i;
            int row = e >> 3, hb = (e & 7) * 8;
            const float* src = x + (size_t)(row0 + row) * 768 + kc * 64 + hb;
            float4 f0 = *(const float4*)(src);
            float4 f1 = *(const float4*)(src + 4);
            short8 pk;
            pk[0] = (short)f2bf(f0.x); pk[1] = (short)f2bf(f0.y);
            pk[2] = (short)f2bf(f0.z); pk[3] = (short)f2bf(f0.w);
            pk[4] = (short)f2bf(f1.x); pk[5] = (short)f2bf(f1.y);
            pk[6] = (short)f2bf(f1.z); pk[7] = (short)f2bf(f1.w);
            *(short8*)&xs[row * 72 + hb] = pk;
        }
        for (int i = 0; i < 2; ++i) {         // stage W chunk 64x64 bf16
            int e = tid + 256 * i;
            int n = e >> 3, kb8 = (e & 7) * 8;
            *(short8*)&wsm[n * 72 + kb8] =
                *(const short8*)&WT[(size_t)(my * 64 + n) * 768 + kc * 64 + kb8];
        }
        __syncthreads();
        for (int kh = 0; kh < 2; ++kh) {
            int kk = kh * 32 + quad * 8;
            short8 a[2], bfr[2];
            for (int mt = 0; mt < 2; ++mt)
                a[mt] = *(const short8*)&xs[(wm * 32 + mt * 16 + l16) * 72 + kk];
            for (int nt = 0; nt < 2; ++nt)
                bfr[nt] = *(const short8*)&wsm[(wn * 32 + nt * 16 + l16) * 72 + kk];
            for (int mt = 0; mt < 2; ++mt)
                for (int nt = 0; nt < 2; ++nt)
                    acc[mt][nt] = __builtin_amdgcn_mfma_f32_16x16x32_bf16(
                        a[mt], bfr[nt], acc[mt][nt], 0, 0, 0);
        }
    }
    __syncthreads();
    for (int mt = 0; mt < 2; ++mt) {
        for (int nt = 0; nt < 2; ++nt) {
            int n = wn * 32 + nt * 16 + l16;      // col in [0,64)
            for (int j = 0; j < 4; ++j) {
                int rloc = wm * 32 + mt * 16 + quad * 4 + j;
                unsigned short bv = f2bf(acc[mt][nt][j]);
                if (my == 0)      qws[(size_t)(row0 + rloc) * 64 + n] = bv;
                else if (my == 1) kws[(size_t)(row0 + rloc) * 64 + n] = bv;
                else              xs[n * 72 + rloc] = bv;   // stash for transpose
            }
        }
    }
    if (my == 2) {
        __syncthreads();
        int bidx = row0 >> 11, t0 = row0 & 2047;
        for (int i = 0; i < 2; ++i) {
            int e = tid + 256 * i;
            int c = e >> 3, rb = (e & 7) * 8;
            *(short8*)&vT[((size_t)(bidx * 64 + c)) * 2048 + t0 + rb] =
                *(const short8*)&xs[c * 72 + rb];
        }
    }
}

// ---- split-K flash attention: grid (64 tiles, 4 batch, 5 splits), 128 thr
__global__ __launch_bounds__(128) void attn_split(const unsigned short* __restrict__ qws,
                                                  const unsigned short* __restrict__ kws,
                                                  const unsigned short* __restrict__ vT,
                                                  float* __restrict__ po,
                                                  float* __restrict__ pm,
                                                  float* __restrict__ pl) {
    int bx = blockIdx.x, b = blockIdx.y, sp = blockIdx.z;
    int kbmax = (bx >> 1) + 1;                    // # key-blocks for this tile
    int nsp = (kbmax + SPLIT_KB - 1) / SPLIT_KB;
    if (sp >= nsp) return;
    int kb_lo = sp * SPLIT_KB;
    int kb_hi = min(kb_lo + SPLIT_KB, kbmax);

    __shared__ unsigned short qs[32 * 72];
    __shared__ unsigned short ks[64 * 72];
    __shared__ unsigned short vs[64 * 72];
    __shared__ unsigned short ps[2][16 * 72];
    int tid = threadIdx.x;
    int lane = tid & 63, wave = tid >> 6;
    int quad = lane >> 4, l16 = lane & 15;
    int q0 = bx * 32;
    size_t qbase = ((size_t)b * 2048 + q0) * 64;
    for (int i = 0; i < 2; ++i) {
        int e = tid + 128 * i;
        int r = e >> 3, hb = (e & 7) * 8;
        *(short8*)&qs[r * 72 + hb] = *(const short8*)&qws[qbase + r * 64 + hb];
    }
    __syncthreads();
    short8 aq[2];
    for (int kh = 0; kh < 2; ++kh)
        aq[kh] = *(const short8*)&qs[(wave * 16 + l16) * 72 + kh * 32 + quad * 8];

    f32x4 o_acc[4];
    for (int nt = 0; nt < 4; ++nt) o_acc[nt] = (f32x4)(0.f);
    float m_run[4], l_run[4];
    int row_g[4];
    for (int j = 0; j < 4; ++j) {
        m_run[j] = -1e30f; l_run[j] = 0.f;
        row_g[j] = q0 + wave * 16 + quad * 4 + j;
    }

    for (int kb = kb_lo; kb < kb_hi; ++kb) {
        __syncthreads();
        size_t kvbase = ((size_t)b * 2048 + kb * 64) * 64;
        for (int i = 0; i < 4; ++i) {
            int e = tid + 128 * i;
            int r = e >> 3, hb = (e & 7) * 8;
            *(short8*)&ks[r * 72 + hb] = *(const short8*)&kws[kvbase + r * 64 + hb];
        }
        for (int i = 0; i < 4; ++i) {
            int e = tid + 128 * i;
            int h = e >> 3, kyb = (e & 7) * 8;
            *(short8*)&vs[h * 72 + kyb] =
                *(const short8*)&vT[((size_t)b * 64 + h) * 2048 + kb * 64 + kyb];
        }
        __syncthreads();
        f32x4 s[4];
        for (int nt = 0; nt < 4; ++nt) s[nt] = (f32x4)(0.f);
        for (int kh = 0; kh < 2; ++kh)
            for (int nt = 0; nt < 4; ++nt) {
                short8 bk = *(const short8*)&ks[(nt * 16 + l16) * 72 + kh * 32 + quad * 8];
                s[nt] = __builtin_amdgcn_mfma_f32_16x16x32_bf16(aq[kh], bk, s[nt], 0, 0, 0);
            }
        if (kb == kbmax - 1) {                    // diagonal block only
            for (int nt = 0; nt < 4; ++nt) {
                int key = kb * 64 + nt * 16 + l16;
                for (int j = 0; j < 4; ++j)
                    if (key > row_g[j]) s[nt][j] = -1e30f;
            }
        }
        float mx[4], al[4], rs[4];
        for (int j = 0; j < 4; ++j)
            mx[j] = fmaxf(fmaxf(s[0][j], s[1][j]), fmaxf(s[2][j], s[3][j]));
        for (int off = 1; off < 16; off <<= 1)
            for (int j = 0; j < 4; ++j)
                mx[j] = fmaxf(mx[j], __shfl_xor(mx[j], off, 16));
        for (int j = 0; j < 4; ++j) {
            float mn = fmaxf(m_run[j], mx[j]);
            al[j] = exp2f(m_run[j] - mn);
            m_run[j] = mn;
            rs[j] = 0.f;
        }
        for (int nt = 0; nt < 4; ++nt)
            for (int j = 0; j < 4; ++j) {
                float p = exp2f(s[nt][j] - m_run[j]);
                rs[j] += p;
                ps[wave][(quad * 4 + j) * 72 + nt * 16 + l16] = f2bf(p);
            }
        for (int off = 1; off < 16; off <<= 1)
            for (int j = 0; j < 4; ++j)
                rs[j] += __shfl_xor(rs[j], off, 16);
        for (int j = 0; j < 4; ++j) l_run[j] = l_run[j] * al[j] + rs[j];
        for (int nt = 0; nt < 4; ++nt)
            for (int j = 0; j < 4; ++j) o_acc[nt][j] *= al[j];
        for (int kh = 0; kh < 2; ++kh) {
            short8 ap = *(const short8*)&ps[wave][l16 * 72 + kh * 32 + quad * 8];
            for (int nt = 0; nt < 4; ++nt) {
                short8 bv = *(const short8*)&vs[(nt * 16 + l16) * 72 + kh * 32 + quad * 8];
                o_acc[nt] = __builtin_amdgcn_mfma_f32_16x16x32_bf16(ap, bv, o_acc[nt], 0, 0, 0);
            }
        }
    }
    // write partials (unnormalized O, plus m,l per row)
    int sbase = ((b * 64 + bx) * MAX_SP + sp) * 32;   // row-slot base
    for (int nt = 0; nt < 4; ++nt)
        for (int j = 0; j < 4; ++j) {
            int r = wave * 16 + quad * 4 + j;
            po[(size_t)(sbase + r) * 64 + nt * 16 + l16] = o_acc[nt][j];
        }
    if (l16 == 0) {
        for (int j = 0; j < 4; ++j) {
            int r = wave * 16 + quad * 4 + j;
            pm[sbase + r] = m_run[j];
            pl[sbase + r] = l_run[j];
        }
    }
}

// ---- combine splits: 1 wave per output row
__global__ __launch_bounds__(256) void reduce_kernel(const float* __restrict__ po,
                                                     const float* __restrict__ pm,
                                                     const float* __restrict__ pl,
                                                     float* __restrict__ out) {
    int tid = threadIdx.x;
    int lane = tid & 63, wave = tid >> 6;
    int g = blockIdx.x * 4 + wave;        // row id [0, 8192)
    int b = g >> 11, t = g & 2047;
    int bx = t >> 5, r = t & 31;
    int kbmax = (bx >> 1) + 1;
    int nsp = (kbmax + SPLIT_KB - 1) / SPLIT_KB;
    int base = ((b * 64 + bx) * MAX_SP) * 32 + r;
    float mstar = -1e30f;
    for (int sp = 0; sp < nsp; ++sp)
        mstar = fmaxf(mstar, pm[base + sp * 32]);
    float acc = 0.f, lsum = 0.f;
    for (int sp = 0; sp < nsp; ++sp) {
        float w = exp2f(pm[base + sp * 32] - mstar);
        acc += w * po[(size_t)(base + sp * 32) * 64 + lane];
        lsum += w * pl[base + sp * 32];
    }
    out[(size_t)g * 64 + lane] = acc / lsum;
}

extern "C" void kernel_launch(void* const* d_in, const int* in_sizes, int n_in,
                              void* d_out, int out_size, void* d_ws, size_t ws_size,
                              hipStream_t stream) {
    const float* x  = (const float*)d_in[0];
    const float* Wk = (const float*)d_in[1];
    const float* Wq = (const float*)d_in[2];
    const float* Wv = (const float*)d_in[3];
    float* out = (float*)d_out;
    // ws layout (bytes):
    //   WT  @ 0        (294912)
    //   qws @ 294912   (1 MB)
    //   kws @ 1343488  (1 MB)
    //   vT  @ 2392064  (1 MB)
    //   po  @ 3440640  (10.49 MB: 4*64*5 slots * 32 rows * 64 h * f32)
    //   pm  @ 13926400 (163840)
    //   pl  @ 14090240 (163840)   total ~13.6 MB
    char* w = (char*)d_ws;
    unsigned short* WT  = (unsigned short*)w;
    unsigned short* qws = (unsigned short*)(w + 294912);
    unsigned short* kws = (unsigned short*)(w + 1343488);
    unsigned short* vT  = (unsigned short*)(w + 2392064);
    float* po = (float*)(w + 3440640);
    float* pm = (float*)(w + 13926400);
    float* pl = (float*)(w + 14090240);
    wt_kernel<<<576, 256, 0, stream>>>(Wk, Wq, Wv, WT);
    proj_kernel<<<dim3(128, 3), 256, 0, stream>>>(x, WT, qws, kws, vT);
    attn_split<<<dim3(64, 4, MAX_SP), 128, 0, stream>>>(qws, kws, vT, po, pm, pl);
    reduce_kernel<<<2048, 256, 0, stream>>>(po, pm, pl, out);
}

// Round 3
// 109.798 us; speedup vs baseline: 2.1561x; 1.0888x over previous
//
#include <hip/hip_runtime.h>
#include <hip/hip_bf16.h>

// Single-head causal attention. B=4, T=2048, E=768, H=64.
// x[4,2048,768] f32; Wk,Wq,Wv [768,64] f32. Out [4,2048,64] f32.
// R3: 3 kernels (wt folded into proj staging). proj: 768 blocks of 32rowsx64cols
// (20 waves/CU). attn: split-K of 4 key-blocks (256 keys) -> 1152 useful blocks
// (9 waves/CU), single-split tiles write out directly. All latency-hiding moves;
// R2 showed no pipe >8% busy.

typedef __attribute__((ext_vector_type(8))) short short8;
typedef __attribute__((ext_vector_type(4))) float f32x4;

#define SPLIT_KB 4          // key-blocks (of 64) per split
#define MAX_SP 8            // ceil(32/4)

__device__ __forceinline__ unsigned short f2bf(float f) {
    union { float f; unsigned u; } v; v.f = f;
    unsigned r = v.u + 0x7fffu + ((v.u >> 16) & 1u);  // RNE
    return (unsigned short)(r >> 16);
}

// ---- projections, grid (256, 3): block = 32 rows x 64 cols of matrix my
// W f32 [768][64] transposed+bf16-converted during staging (wt kernel removed).
__global__ __launch_bounds__(256) void proj_kernel(const float* __restrict__ x,
                                                   const float* __restrict__ Wk,
                                                   const float* __restrict__ Wq,
                                                   const float* __restrict__ Wv,
                                                   unsigned short* __restrict__ qws,
                                                   unsigned short* __restrict__ kws,
                                                   unsigned short* __restrict__ vT) {
    __shared__ unsigned short xs[32 * 72];    // [row][k]
    __shared__ unsigned short wsm[64 * 72];   // [n][k] (transposed W chunk)
    const float CSCALE = 1.4426950408889634f / 27.712812921102035f;  // log2e/sqrt(768)
    int tid = threadIdx.x;
    int lane = tid & 63, wave = tid >> 6;
    int quad = lane >> 4, l16 = lane & 15;
    int row0 = blockIdx.x * 32;
    int my = blockIdx.y;                      // 0=q 1=k 2=v
    const float* W = (my == 0) ? Wq : (my == 1) ? Wk : Wv;

    // staging indices
    int xrow = tid >> 3, xcb = (tid & 7) * 8;         // x: 8 f32 per thread
    int wn = tid & 63, wk0 = (tid >> 6) * 16;         // W: 16 k's for fixed n

    f32x4 acc[2];
    acc[0] = (f32x4)(0.f); acc[1] = (f32x4)(0.f);

    for (int kc = 0; kc < 12; ++kc) {
        __syncthreads();
        {   // stage x 32x64 f32 -> bf16
            const float* src = x + (size_t)(row0 + xrow) * 768 + kc * 64 + xcb;
            float4 f0 = *(const float4*)(src);
            float4 f1 = *(const float4*)(src + 4);
            short8 pk;
            pk[0] = (short)f2bf(f0.x); pk[1] = (short)f2bf(f0.y);
            pk[2] = (short)f2bf(f0.z); pk[3] = (short)f2bf(f0.w);
            pk[4] = (short)f2bf(f1.x); pk[5] = (short)f2bf(f1.y);
            pk[6] = (short)f2bf(f1.z); pk[7] = (short)f2bf(f1.w);
            *(short8*)&xs[xrow * 72 + xcb] = pk;
        }
        {   // stage W chunk transposed: wsm[n][k] = W[kc*64+k][n]
            float wv[16];
            for (int i = 0; i < 16; ++i)
                wv[i] = W[(size_t)(kc * 64 + wk0 + i) * 64 + wn];
            if (my == 0)
                for (int i = 0; i < 16; ++i) wv[i] *= CSCALE;
            short8 p0, p1;
            for (int i = 0; i < 8; ++i) { p0[i] = (short)f2bf(wv[i]); p1[i] = (short)f2bf(wv[8 + i]); }
            *(short8*)&wsm[wn * 72 + wk0] = p0;
            *(short8*)&wsm[wn * 72 + wk0 + 8] = p1;
        }
        __syncthreads();
        for (int kh = 0; kh < 2; ++kh) {
            int kk = kh * 32 + quad * 8;
            short8 bfr = *(const short8*)&wsm[(wave * 16 + l16) * 72 + kk];
            for (int mt = 0; mt < 2; ++mt) {
                short8 a = *(const short8*)&xs[(mt * 16 + l16) * 72 + kk];
                acc[mt] = __builtin_amdgcn_mfma_f32_16x16x32_bf16(a, bfr, acc[mt], 0, 0, 0);
            }
        }
    }
    __syncthreads();
    int n = wave * 16 + l16;                  // col in [0,64)
    if (my != 2) {
        unsigned short* dst = (my == 0) ? qws : kws;
        for (int mt = 0; mt < 2; ++mt)
            for (int j = 0; j < 4; ++j) {
                int rloc = mt * 16 + quad * 4 + j;
                dst[(size_t)(row0 + rloc) * 64 + n] = f2bf(acc[mt][j]);
            }
    } else {
        // stash V transposed in wsm[c][r] (stride 40), then 16B writes to vT
        for (int mt = 0; mt < 2; ++mt)
            for (int j = 0; j < 4; ++j) {
                int rloc = mt * 16 + quad * 4 + j;
                wsm[n * 40 + rloc] = f2bf(acc[mt][j]);
            }
        __syncthreads();
        int bidx = row0 >> 11, t0 = row0 & 2047;
        int c = tid >> 2, rb = (tid & 3) * 8;
        *(short8*)&vT[((size_t)(bidx * 64 + c)) * 2048 + t0 + rb] =
            *(const short8*)&wsm[c * 40 + rb];
    }
}

// ---- split-K flash attention: grid (64 tiles, 4 batch, 8 splits), 128 thr
__global__ __launch_bounds__(128) void attn_split(const unsigned short* __restrict__ qws,
                                                  const unsigned short* __restrict__ kws,
                                                  const unsigned short* __restrict__ vT,
                                                  float* __restrict__ po,
                                                  float* __restrict__ pm,
                                                  float* __restrict__ pl,
                                                  float* __restrict__ out) {
    int bx = blockIdx.x, b = blockIdx.y, sp = blockIdx.z;
    int kbmax = (bx >> 1) + 1;                    // # key-blocks for this tile
    int nsp = (kbmax + SPLIT_KB - 1) / SPLIT_KB;
    if (sp >= nsp) return;
    int kb_lo = sp * SPLIT_KB;
    int kb_hi = min(kb_lo + SPLIT_KB, kbmax);

    __shared__ unsigned short qs[32 * 72];
    __shared__ unsigned short ks[64 * 72];
    __shared__ unsigned short vs[64 * 72];
    __shared__ unsigned short ps[2][16 * 72];
    int tid = threadIdx.x;
    int lane = tid & 63, wave = tid >> 6;
    int quad = lane >> 4, l16 = lane & 15;
    int q0 = bx * 32;
    size_t qbase = ((size_t)b * 2048 + q0) * 64;
    for (int i = 0; i < 2; ++i) {
        int e = tid + 128 * i;
        int r = e >> 3, hb = (e & 7) * 8;
        *(short8*)&qs[r * 72 + hb] = *(const short8*)&qws[qbase + r * 64 + hb];
    }
    __syncthreads();
    short8 aq[2];
    for (int kh = 0; kh < 2; ++kh)
        aq[kh] = *(const short8*)&qs[(wave * 16 + l16) * 72 + kh * 32 + quad * 8];

    f32x4 o_acc[4];
    for (int nt = 0; nt < 4; ++nt) o_acc[nt] = (f32x4)(0.f);
    float m_run[4], l_run[4];
    int row_g[4];
    for (int j = 0; j < 4; ++j) {
        m_run[j] = -1e30f; l_run[j] = 0.f;
        row_g[j] = q0 + wave * 16 + quad * 4 + j;
    }

    for (int kb = kb_lo; kb < kb_hi; ++kb) {
        __syncthreads();
        size_t kvbase = ((size_t)b * 2048 + kb * 64) * 64;
        for (int i = 0; i < 4; ++i) {
            int e = tid + 128 * i;
            int r = e >> 3, hb = (e & 7) * 8;
            *(short8*)&ks[r * 72 + hb] = *(const short8*)&kws[kvbase + r * 64 + hb];
        }
        for (int i = 0; i < 4; ++i) {
            int e = tid + 128 * i;
            int h = e >> 3, kyb = (e & 7) * 8;
            *(short8*)&vs[h * 72 + kyb] =
                *(const short8*)&vT[((size_t)b * 64 + h) * 2048 + kb * 64 + kyb];
        }
        __syncthreads();
        f32x4 s[4];
        for (int nt = 0; nt < 4; ++nt) s[nt] = (f32x4)(0.f);
        for (int kh = 0; kh < 2; ++kh)
            for (int nt = 0; nt < 4; ++nt) {
                short8 bk = *(const short8*)&ks[(nt * 16 + l16) * 72 + kh * 32 + quad * 8];
                s[nt] = __builtin_amdgcn_mfma_f32_16x16x32_bf16(aq[kh], bk, s[nt], 0, 0, 0);
            }
        if (kb == kbmax - 1) {                    // diagonal block only
            for (int nt = 0; nt < 4; ++nt) {
                int key = kb * 64 + nt * 16 + l16;
                for (int j = 0; j < 4; ++j)
                    if (key > row_g[j]) s[nt][j] = -1e30f;
            }
        }
        float mx[4], al[4], rs[4];
        for (int j = 0; j < 4; ++j)
            mx[j] = fmaxf(fmaxf(s[0][j], s[1][j]), fmaxf(s[2][j], s[3][j]));
        for (int off = 1; off < 16; off <<= 1)
            for (int j = 0; j < 4; ++j)
                mx[j] = fmaxf(mx[j], __shfl_xor(mx[j], off, 16));
        for (int j = 0; j < 4; ++j) {
            float mn = fmaxf(m_run[j], mx[j]);
            al[j] = exp2f(m_run[j] - mn);
            m_run[j] = mn;
            rs[j] = 0.f;
        }
        for (int nt = 0; nt < 4; ++nt)
            for (int j = 0; j < 4; ++j) {
                float p = exp2f(s[nt][j] - m_run[j]);
                rs[j] += p;
                ps[wave][(quad * 4 + j) * 72 + nt * 16 + l16] = f2bf(p);
            }
        for (int off = 1; off < 16; off <<= 1)
            for (int j = 0; j < 4; ++j)
                rs[j] += __shfl_xor(rs[j], off, 16);
        for (int j = 0; j < 4; ++j) l_run[j] = l_run[j] * al[j] + rs[j];
        for (int nt = 0; nt < 4; ++nt)
            for (int j = 0; j < 4; ++j) o_acc[nt][j] *= al[j];
        for (int kh = 0; kh < 2; ++kh) {
            short8 ap = *(const short8*)&ps[wave][l16 * 72 + kh * 32 + quad * 8];
            for (int nt = 0; nt < 4; ++nt) {
                short8 bv = *(const short8*)&vs[(nt * 16 + l16) * 72 + kh * 32 + quad * 8];
                o_acc[nt] = __builtin_amdgcn_mfma_f32_16x16x32_bf16(ap, bv, o_acc[nt], 0, 0, 0);
            }
        }
    }
    if (nsp == 1) {
        // single split: final result, write normalized output directly
        for (int nt = 0; nt < 4; ++nt)
            for (int j = 0; j < 4; ++j)
                out[((size_t)b * 2048 + row_g[j]) * 64 + nt * 16 + l16] =
                    o_acc[nt][j] / l_run[j];
        return;
    }
    int sbase = ((b * 64 + bx) * MAX_SP + sp) * 32;   // row-slot base
    for (int nt = 0; nt < 4; ++nt)
        for (int j = 0; j < 4; ++j) {
            int r = wave * 16 + quad * 4 + j;
            po[(size_t)(sbase + r) * 64 + nt * 16 + l16] = o_acc[nt][j];
        }
    if (l16 == 0) {
        for (int j = 0; j < 4; ++j) {
            int r = wave * 16 + quad * 4 + j;
            pm[sbase + r] = m_run[j];
            pl[sbase + r] = l_run[j];
        }
    }
}

// ---- combine splits: 1 wave per output row (rows with nsp==1 already done)
__global__ __launch_bounds__(256) void reduce_kernel(const float* __restrict__ po,
                                                     const float* __restrict__ pm,
                                                     const float* __restrict__ pl,
                                                     float* __restrict__ out) {
    int tid = threadIdx.x;
    int lane = tid & 63, wave = tid >> 6;
    int g = blockIdx.x * 4 + wave;        // row id [0, 8192)
    int b = g >> 11, t = g & 2047;
    int bx = t >> 5, r = t & 31;
    int kbmax = (bx >> 1) + 1;
    int nsp = (kbmax + SPLIT_KB - 1) / SPLIT_KB;
    if (nsp == 1) return;                 // written by attn_split directly
    int base = ((b * 64 + bx) * MAX_SP) * 32 + r;
    float mstar = -1e30f;
    for (int sp = 0; sp < nsp; ++sp)
        mstar = fmaxf(mstar, pm[base + sp * 32]);
    float acc = 0.f, lsum = 0.f;
    for (int sp = 0; sp < nsp; ++sp) {
        float w = exp2f(pm[base + sp * 32] - mstar);
        acc += w * po[(size_t)(base + sp * 32) * 64 + lane];
        lsum += w * pl[base + sp * 32];
    }
    out[(size_t)g * 64 + lane] = acc / lsum;
}

extern "C" void kernel_launch(void* const* d_in, const int* in_sizes, int n_in,
                              void* d_out, int out_size, void* d_ws, size_t ws_size,
                              hipStream_t stream) {
    const float* x  = (const float*)d_in[0];
    const float* Wk = (const float*)d_in[1];
    const float* Wq = (const float*)d_in[2];
    const float* Wv = (const float*)d_in[3];
    float* out = (float*)d_out;
    // ws layout (bytes):
    //   qws @ 0         (1 MB)
    //   kws @ 1048576   (1 MB)
    //   vT  @ 2097152   (1 MB)
    //   po  @ 3145728   (16.78 MB: 4*64*8 slots * 32 rows * 64 h * f32)
    //   pm  @ 19922944  (262144)
    //   pl  @ 20185088  (262144)   total ~19.5 MB
    char* w = (char*)d_ws;
    unsigned short* qws = (unsigned short*)w;
    unsigned short* kws = (unsigned short*)(w + 1048576);
    unsigned short* vT  = (unsigned short*)(w + 2097152);
    float* po = (float*)(w + 3145728);
    float* pm = (float*)(w + 19922944);
    float* pl = (float*)(w + 20185088);
    proj_kernel<<<dim3(256, 3), 256, 0, stream>>>(x, Wk, Wq, Wv, qws, kws, vT);
    attn_split<<<dim3(64, 4, MAX_SP), 128, 0, stream>>>(qws, kws, vT, po, pm, pl, out);
    reduce_kernel<<<2048, 256, 0, stream>>>(po, pm, pl, out);
}